// Round 15
// baseline (207.738 us; speedup 1.0000x reference)
//
#include <hip/hip_runtime.h>
#include <math.h>

// Model: B=32, C=64, T=1024, H=10, OUT=2.
// R29 post-mortem: WIN 103.7->98.1us (pk-fma halved parallel FMA issue).
// Split: parallel ~35us, scan ~63us (64%). Scan is at its ~28-instr/step
// issue floor for the always-compute form.
// R30 = R29 + ONE change: SPIKE-SKIP scan. rec = sum z_j*w_j is exactly 0
// when no neuron spiked at t-1; that dot (10 readlane + 10 fma + add,
// ~75% of the step) is skipped behind a wave-uniform anyspike flag
// (__any(z), uniform s_cbranch, no divergence).
//  - Ghost lanes 10-63 now load W_rec ROW 0 (same slot-0 iin) -> they
//    replicate neuron 0 exactly -> __any(z) == "any real spike". Their S
//    is discarded by the lane<H output guard.
//  - Skip path bit-exact: skipped fmas add +-0; acc provably never -0
//    (Iin sums give +0; x+(-x)=+0 under RN) -> acc + 0 = acc exactly.
// Predict (data-dep): f = spike-free fraction; dur 98 -> ~84-88 if f~0.5,
// ~94 if f~0.2, bounded ~101 if f~0 (revert). absmax 0.0 HARD GATE.

constexpr int B = 32, C = 64, T = 1024, H = 10;
constexpr int NT = 512;   // threads per block (8 waves)
constexpr int RS = 1028;  // scan-row stride (floats): 16B-aligned

using v2f = float __attribute__((ext_vector_type(2)));
__device__ inline v2f v2(float s) { v2f r; r.x = s; r.y = s; return r; }
__device__ inline v2f vfma(v2f a, v2f b, v2f c) {
  return __builtin_elementwise_fma(a, b, c);   // v_pk_fma_f32
}

struct Params {
  const float *beeg, *W_ef, *b_ef, *g_i, *be_i, *Wq, *g_q, *be_q, *Wk, *g_k,
      *be_k, *Wv, *g_v, *be_v, *Wc, *g_c, *be_c, *W_in, *W_rec, *W_cls, *b_cls;
  int* cnt;              // barrier counters (memset 0 each launch)
  double *P1, *P2, *P3;  // cross-block stat partials, layout [ch][32]
  float* out;
};

// DPP wave64 sum: result valid in lane 63 (VALU pipe, no DS traffic).
template <int CTRL>
__device__ inline float dadd(float v) {
  int x = __builtin_amdgcn_update_dpp(0, __float_as_int(v), CTRL, 0xf, 0xf,
                                      true);
  return v + __int_as_float(x);
}
__device__ inline float wred63(float v) {
  v = dadd<0x111>(v);  // row_shr:1
  v = dadd<0x112>(v);  // row_shr:2
  v = dadd<0x114>(v);  // row_shr:4
  v = dadd<0x118>(v);  // row_shr:8
  v = dadd<0x142>(v);  // row_bcast:15
  v = dadd<0x143>(v);  // row_bcast:31
  return v;            // lane 63 = full sum
}

// fast tanh: 1 - 2/(e^{2x}+1) via native exp2/rcp. ~1e-7 abs, branch-free.
// PROVEN absmax 0.0 in R23-R29.
__device__ inline float ftanh(float x) {
  float e = __builtin_amdgcn_exp2f(x * 2.8853900817779268f);  // e^{2x}
  float r = __builtin_amdgcn_rcpf(e + 1.0f);
  return fmaf(-2.0f, r, 1.0f);
}

// 32-block barrier, fence-free (all cross-block data via agent-scope atomics).
__device__ inline void gbar(int* cnt, int phase, int tid) {
  __syncthreads();
  if (tid == 0) {
    __hip_atomic_fetch_add(&cnt[phase], 1, __ATOMIC_RELEASE,
                           __HIP_MEMORY_SCOPE_AGENT);
    while (__hip_atomic_load(&cnt[phase], __ATOMIC_RELAXED,
                             __HIP_MEMORY_SCOPE_AGENT) < B)
      __builtin_amdgcn_s_sleep(2);
  }
  __syncthreads();
}

__global__ void __launch_bounds__(NT) fused22(Params p) {
  const int b = blockIdx.x, tid = threadIdx.x;
  const int lane = tid & 63, wid = tid >> 6;   // 8 waves
  const int t0 = tid, t1 = tid + NT;

  __shared__ __align__(16) float slab[T * 11];   // scratch, then Iin [h][RS]
  __shared__ __align__(16) float gtab[T];        // 4KB
  __shared__ double dred2[60 * 17 + 4];          // combine partials (pad 17)
  __shared__ double dtot[60];
  __shared__ float stM[30], stI[30], Ms[100], Nl[100];

  // slab scratch layout (all dead before S5 overwrites the whole slab):
  //  swred [0,480) | kxt [0,10240) (lifetime-disjoint) | mpw [10240,11040)
  float* swred = slab;
  float* kxt   = slab;
  float* mpw   = slab + 10240;

  // g[t] = (9(1-0.9^{T-t}) - 4(1-0.8^{T-t})) / T  (f32 closed form)
  {
    const float L2A = -0.15200309344504995f;   // log2(0.9)
    const float L2D = -0.32192809488736235f;   // log2(0.8)
    float m0 = (float)(T - t0), m1 = (float)(T - t1);
    gtab[t0] = (9.0f * (1.0f - exp2f(m0 * L2A)) -
                4.0f * (1.0f - exp2f(m0 * L2D))) * (1.0f / (float)T);
    gtab[t1] = (9.0f * (1.0f - exp2f(m1 * L2A)) -
                4.0f * (1.0f - exp2f(m1 * L2D))) * (1.0f / (float)T);
  }

  // parallel stats combine: P layout [ch][32]; ch x 16 workers, 2 loads each.
  auto combine = [&](double* P, int Q2) {
    for (int id = tid; id < Q2 * 16; id += NT) {
      int ch = id >> 4, i = id & 15;
      double s = __hip_atomic_load(&P[ch * 32 + i], __ATOMIC_RELAXED,
                                   __HIP_MEMORY_SCOPE_AGENT) +
                 __hip_atomic_load(&P[ch * 32 + 16 + i], __ATOMIC_RELAXED,
                                   __HIP_MEMORY_SCOPE_AGENT);
      dred2[ch * 17 + i] = s;
    }
    __syncthreads();
    if (tid < Q2) {
      double s = 0.0;
#pragma unroll
      for (int i = 0; i < 16; ++i) s += dred2[tid * 17 + i];
      dtot[tid] = s;
    }
    __syncthreads();
  };

  // ---------------- S1: embed (weights via uniform/scalar loads; pk-fma)
  v2f p1[H];
#pragma unroll
  for (int h = 0; h < H; ++h) p1[h] = v2(p.b_ef[h]);
  {
    const float* bp = p.beeg + (size_t)b * C * T;
#pragma unroll 8
    for (int c = 0; c < C; ++c) {
      v2f vab;
      vab.x = bp[(size_t)c * T + t0];
      vab.y = bp[(size_t)c * T + t1];
#pragma unroll
      for (int h = 0; h < H; ++h)
        p1[h] = vfma(vab, v2(p.W_ef[h * C + c]), p1[h]);
    }
  }
#pragma unroll
  for (int h = 0; h < H; ++h) {
    float r1 = wred63(p1[h].x + p1[h].y);
    float r2 = wred63(p1[h].x * p1[h].x + p1[h].y * p1[h].y);
    if (lane == 63) { swred[wid * 60 + h] = r1; swred[wid * 60 + 10 + h] = r2; }
  }
  __syncthreads();
  if (tid < 20) {
    float s = 0.f;
#pragma unroll
    for (int w = 0; w < 8; ++w) s += swred[w * 60 + tid];
    __hip_atomic_store(&p.P1[tid * 32 + b], (double)s, __ATOMIC_RELAXED,
                       __HIP_MEMORY_SCOPE_AGENT);
  }
  gbar(p.cnt, 0, tid);
  combine(p.P1, 20);
  if (tid < 10) {
    double mean = dtot[tid] * (1.0 / 32768.0);
    double var  = dtot[10 + tid] * (1.0 / 32768.0) - mean * mean;
    stM[tid] = (float)mean;
    stI[tid] = (float)(1.0 / sqrt(var + 1e-5));
  }
  __syncthreads();

  // ---------------- S2: x = tanh(bn(pre1)); qkv stats (pk-fma accums)
  v2f xv[H];
#pragma unroll
  for (int j = 0; j < H; ++j) {
    xv[j].x = ftanh(p.g_i[j] * (p1[j].x - stM[j]) * stI[j] + p.be_i[j]);
    xv[j].y = ftanh(p.g_i[j] * (p1[j].y - stM[j]) * stI[j] + p.be_i[j]);
  }
  // p1 dead; only xv (10 v2f) persists from here on.
#pragma unroll
  for (int h = 0; h < H; ++h) {
    v2f q = v2(0.f), k = v2(0.f), v = v2(0.f);
#pragma unroll
    for (int j = 0; j < H; ++j) {
      q = vfma(xv[j], v2(p.Wq[h * H + j]), q);
      k = vfma(xv[j], v2(p.Wk[h * H + j]), k);
      v = vfma(xv[j], v2(p.Wv[h * H + j]), v);
    }
    float r1 = wred63(q.x + q.y), r2 = wred63(q.x * q.x + q.y * q.y);
    float r3 = wred63(k.x + k.y), r4 = wred63(k.x * k.x + k.y * k.y);
    float r5 = wred63(v.x + v.y), r6 = wred63(v.x * v.x + v.y * v.y);
    if (lane == 63) {
      swred[wid * 60 + h]      = r1; swred[wid * 60 + 30 + h] = r2;
      swred[wid * 60 + 10 + h] = r3; swred[wid * 60 + 40 + h] = r4;
      swred[wid * 60 + 20 + h] = r5; swred[wid * 60 + 50 + h] = r6;
    }
  }
  __syncthreads();
  if (tid < 60) {
    float s = 0.f;
#pragma unroll
    for (int w = 0; w < 8; ++w) s += swred[w * 60 + tid];
    __hip_atomic_store(&p.P2[tid * 32 + b], (double)s, __ATOMIC_RELAXED,
                       __HIP_MEMORY_SCOPE_AGENT);
  }
  gbar(p.cnt, 1, tid);
  combine(p.P2, 60);
  if (tid < 30) {
    double mean = dtot[tid] * (1.0 / 32768.0);
    double var  = dtot[30 + tid] * (1.0 / 32768.0) - mean * mean;
    stM[tid] = (float)mean;
    stI[tid] = (float)(1.0 / sqrt(var + 1e-5));
  }
  __syncthreads();   // swred reads done; kxt may now overwrite [0,480)

  // ---------------- S3: M = KV^T, merged single pass (R28 structure,
  // pk-fma mats). kxt transposed [20][512]: conflict-free.
  {
    v2f vx[H];   // (vxa, vxb)
#pragma unroll
    for (int h = 0; h < H; ++h) {
      v2f k = v2(0.f), v = v2(0.f);
#pragma unroll
      for (int j = 0; j < H; ++j) {
        k = vfma(xv[j], v2(p.Wk[h * H + j]), k);
        v = vfma(xv[j], v2(p.Wv[h * H + j]), v);
      }
      kxt[h * NT + tid] =
          fmaxf(p.g_k[h] * (k.x - stM[10 + h]) * stI[10 + h] + p.be_k[h], 0.f);
      kxt[(H + h) * NT + tid] =
          fmaxf(p.g_k[h] * (k.y - stM[10 + h]) * stI[10 + h] + p.be_k[h], 0.f);
      vx[h].x = ftanh(p.g_v[h] * (v.x - stM[20 + h]) * stI[20 + h] + p.be_v[h]);
      vx[h].y = ftanh(p.g_v[h] * (v.y - stM[20 + h]) * stI[20 + h] + p.be_v[h]);
    }
    __syncthreads();   // kxt writes visible (also orders vs swred aliasing)
#pragma unroll 1
    for (int i = 0; i < H; ++i) {
      float kia = kxt[i * NT + tid];
      float kib = kxt[(H + i) * NT + tid];
#pragma unroll
      for (int j = 0; j < H; ++j) {
        float r = wred63(fmaf(kia, vx[j].x, kib * vx[j].y));
        if (lane == 63) mpw[wid * 100 + i * 10 + j] = r;
      }
    }
  }
  __syncthreads();
  if (tid < 100) {
    float s = 0.f;
#pragma unroll
    for (int w = 0; w < 8; ++w) s += mpw[w * 100 + tid];
    Ms[tid] = s;
  }
  __syncthreads();

  // ---------------- S4: N = (M Wc^T)/H; recompute q; prec = q.N (pk)
  if (tid < 100) {
    int i = tid / 10, h = tid % 10;
    float a = 0.f;
#pragma unroll
    for (int j = 0; j < H; ++j) a = fmaf(Ms[i * 10 + j], p.Wc[h * H + j], a);
    Nl[tid] = a * 0.1f;
  }
  __syncthreads();
  v2f pc[H];
  {
    v2f qv[H];
#pragma unroll
    for (int h = 0; h < H; ++h) {
      v2f qa = v2(0.f);
#pragma unroll
      for (int j = 0; j < H; ++j) qa = vfma(xv[j], v2(p.Wq[h * H + j]), qa);
      qv[h].x = fmaxf(p.g_q[h] * (qa.x - stM[h]) * stI[h] + p.be_q[h], 0.f);
      qv[h].y = fmaxf(p.g_q[h] * (qa.y - stM[h]) * stI[h] + p.be_q[h], 0.f);
    }
#pragma unroll
    for (int h = 0; h < H; ++h) {
      v2f a = v2(0.f);
#pragma unroll
      for (int i = 0; i < H; ++i) a = vfma(qv[i], v2(Nl[i * 10 + h]), a);
      pc[h] = a;
    }
  }
  // xv dead now; pc (10 v2f) live.
#pragma unroll
  for (int h = 0; h < H; ++h) {
    float r1 = wred63(pc[h].x + pc[h].y);
    float r2 = wred63(pc[h].x * pc[h].x + pc[h].y * pc[h].y);
    if (lane == 63) { swred[wid * 60 + h] = r1; swred[wid * 60 + 10 + h] = r2; }
  }
  __syncthreads();
  if (tid < 20) {
    float s = 0.f;
#pragma unroll
    for (int w = 0; w < 8; ++w) s += swred[w * 60 + tid];
    __hip_atomic_store(&p.P3[tid * 32 + b], (double)s, __ATOMIC_RELAXED,
                       __HIP_MEMORY_SCOPE_AGENT);
  }
  gbar(p.cnt, 2, tid);
  combine(p.P3, 20);
  if (tid < 10) {
    double mean = dtot[tid] * (1.0 / 32768.0);
    double var  = dtot[10 + tid] * (1.0 / 32768.0) - mean * mean;
    stM[tid] = (float)mean;
    stI[tid] = (float)(1.0 / sqrt(var + 1e-5));
  }
  __syncthreads();   // all slab-scratch reads done before S5 overwrites

  // ---------------- S5: bn+relu, Iin into LDS rows [h][RS] (pk-fma)
  {
    v2f ca[H];
#pragma unroll
    for (int j = 0; j < H; ++j) {
      ca[j].x = fmaxf(p.g_c[j] * (pc[j].x - stM[j]) * stI[j] + p.be_c[j], 0.f);
      ca[j].y = fmaxf(p.g_c[j] * (pc[j].y - stM[j]) * stI[j] + p.be_c[j], 0.f);
    }
#pragma unroll
    for (int h = 0; h < H; ++h) {
      v2f a = v2(0.f);
#pragma unroll
      for (int j = 0; j < H; ++j) a = vfma(ca[j], v2(p.W_in[h * H + j]), a);
      slab[h * RS + t0] = a.x;
      slab[h * RS + t1] = a.y;
    }
  }
  __syncthreads();

  // ---------------- S6: LSNN scan, wave 0 only; SPIKE-SKIP rec dot.
  if (tid < 64) {
    // gtot closed form: .9^1024/.8^1024 underflow -> (5*1024 - 81 + 16)/1024
    const float gtot = 4.9365234375f;

    const int slot = lane < H ? lane : 0;   // inactive lanes broadcast row 0
    const float* row = slab + slot * RS;
    float wrf[H];  // W_rec row; ghost lanes (>=10) load ROW 0 so they
                   // replicate neuron 0 exactly -> __any(z) == any real spike
#pragma unroll
    for (int j = 0; j < H; ++j)
      wrf[j] = p.W_rec[slot * H + j];

    float accp = 0.f, vm = 0.f, S = 0.f;    // accp = i_jump of prev step
    float zf = 0.f;   // prev-step spike, per-lane float (lane j holds z_j)
    bool anyspike = false;   // wave-uniform: any z at t-1 (all lanes agree)

    auto step = [&](float iin, float gt) {
      float acc = fmaf(0.8f, accp, iin);    // fused decay
      if (anyspike) {
        // rec dot only when nonzero: 10 readlane + dual fma chains.
        // Skip path is bit-exact (skipped fmas add +-0; acc never -0).
        float zj[H];
#pragma unroll
        for (int j = 0; j < H; ++j)
          zj[j] = __int_as_float(
              __builtin_amdgcn_readlane(__float_as_int(zf), j));
        float acc0 = acc, acc1 = 0.f;
#pragma unroll
        for (int j = 0; j < H; j += 2) {
          acc0 = fmaf(zj[j],     wrf[j],     acc0);
          acc1 = fmaf(zj[j + 1], wrf[j + 1], acc1);
        }
        acc = acc0 + acc1;
      }
      float v_dec = fmaf(0.1f, acc - vm, vm);  // vm + 0.1*(i_jump - vm)
      bool z = v_dec > 0.5f;
      anyspike = __any(z);                     // uniform (ghosts mirror n0)
      vm = z ? 0.f : v_dec;
      zf = z ? 1.0f : 0.0f;
      S = fmaf(zf, gt, S);                     // exact: +gt or +0.0
      accp = acc;
    };

    float4 iA = *(const float4*)&row[0];
    float4 iB = *(const float4*)&row[4];
    float4 gA = *(const float4*)&gtab[0], gB = *(const float4*)&gtab[4];

    for (int t8 = 0; t8 < T - 8; t8 += 8) {
      float4 iN1 = *(const float4*)&row[t8 + 8];
      float4 iN2 = *(const float4*)&row[t8 + 12];
      float4 gN1 = *(const float4*)&gtab[t8 + 8];
      float4 gN2 = *(const float4*)&gtab[t8 + 12];
      step(iA.x, gA.x); step(iA.y, gA.y); step(iA.z, gA.z); step(iA.w, gA.w);
      step(iB.x, gB.x); step(iB.y, gB.y); step(iB.z, gB.z); step(iB.w, gB.w);
      iA = iN1; iB = iN2; gA = gN1; gB = gN2;
    }
    step(iA.x, gA.x); step(iA.y, gA.y); step(iA.z, gA.z); step(iA.w, gA.w);
    step(iB.x, gB.x); step(iB.y, gB.y); step(iB.z, gB.z); step(iB.w, gB.w);

    int li = lane < H ? lane : 0;
    float c0 = (lane < H) ? S * p.W_cls[li]     : 0.f;
    float c1 = (lane < H) ? S * p.W_cls[H + li] : 0.f;
    float r0 = wred63(c0), r1 = wred63(c1);
    if (lane == 63) {
      p.out[b * 2 + 0] = r0 + gtot * p.b_cls[0];
      p.out[b * 2 + 1] = r1 + gtot * p.b_cls[1];
    }
  }
}

extern "C" void kernel_launch(void* const* d_in, const int* in_sizes, int n_in,
                              void* d_out, int out_size, void* d_ws, size_t ws_size,
                              hipStream_t stream) {
  Params p;
  p.beeg  = (const float*)d_in[2];
  p.W_ef  = (const float*)d_in[4];
  p.b_ef  = (const float*)d_in[5];
  p.g_i   = (const float*)d_in[6];
  p.be_i  = (const float*)d_in[7];
  p.Wq    = (const float*)d_in[8];
  p.g_q   = (const float*)d_in[9];
  p.be_q  = (const float*)d_in[10];
  p.Wk    = (const float*)d_in[11];
  p.g_k   = (const float*)d_in[12];
  p.be_k  = (const float*)d_in[13];
  p.Wv    = (const float*)d_in[14];
  p.g_v   = (const float*)d_in[15];
  p.be_v  = (const float*)d_in[16];
  p.Wc    = (const float*)d_in[17];
  p.g_c   = (const float*)d_in[18];
  p.be_c  = (const float*)d_in[19];
  p.W_in  = (const float*)d_in[20];
  p.W_rec = (const float*)d_in[21];
  p.W_cls = (const float*)d_in[22];
  p.b_cls = (const float*)d_in[23];

  char* ws = (char*)d_ws;
  p.cnt = (int*)ws;                            // 3 counters, memset below
  p.P1  = (double*)(ws + 256);                 // [20][32] doubles
  p.P2  = (double*)(ws + 256 + 5120);          // [60][32] doubles
  p.P3  = (double*)(ws + 256 + 5120 + 15360);  // [20][32] doubles
  p.out = (float*)d_out;

  (void)hipMemsetAsync(d_ws, 0, 256, stream);  // zero barrier counters
  fused22<<<dim3(B), dim3(NT), 0, stream>>>(p);
}

// Round 16
// 202.645 us; speedup vs baseline: 1.0251x; 1.0251x over previous
//
#include <hip/hip_runtime.h>
#include <math.h>

// Model: B=32, C=64, T=1024, H=10, OUT=2.
// R30 post-mortem: spike-skip REGRESSED 98.1->104.2 (absmax 0.0 held).
// Spikes are DENSE in time (f~0: some neuron fires ~every step), so the
// anyspike flag was pure overhead. Spike-skip retired.
// R31 = R29 byte-for-byte (98.1us proven) + ONE bit-exact scan trim:
// ping-pong 16-step unroll removes the 4 float4 buffer copies
// (16 v_mov / 8 steps = 2 instr/step ~= 3.6us at 4.2 cyc/instr).
// Same loads, same step order -> bit-exact by construction.
// Predict: dur ~94-97 (or ~98 if compiler already renamed the copies),
// VGPR ~88-96, WRITE ~104KB, conflicts 0, absmax 0.0.

constexpr int B = 32, C = 64, T = 1024, H = 10;
constexpr int NT = 512;   // threads per block (8 waves)
constexpr int RS = 1028;  // scan-row stride (floats): 16B-aligned

using v2f = float __attribute__((ext_vector_type(2)));
__device__ inline v2f v2(float s) { v2f r; r.x = s; r.y = s; return r; }
__device__ inline v2f vfma(v2f a, v2f b, v2f c) {
  return __builtin_elementwise_fma(a, b, c);   // v_pk_fma_f32
}

struct Params {
  const float *beeg, *W_ef, *b_ef, *g_i, *be_i, *Wq, *g_q, *be_q, *Wk, *g_k,
      *be_k, *Wv, *g_v, *be_v, *Wc, *g_c, *be_c, *W_in, *W_rec, *W_cls, *b_cls;
  int* cnt;              // barrier counters (memset 0 each launch)
  double *P1, *P2, *P3;  // cross-block stat partials, layout [ch][32]
  float* out;
};

// DPP wave64 sum: result valid in lane 63 (VALU pipe, no DS traffic).
template <int CTRL>
__device__ inline float dadd(float v) {
  int x = __builtin_amdgcn_update_dpp(0, __float_as_int(v), CTRL, 0xf, 0xf,
                                      true);
  return v + __int_as_float(x);
}
__device__ inline float wred63(float v) {
  v = dadd<0x111>(v);  // row_shr:1
  v = dadd<0x112>(v);  // row_shr:2
  v = dadd<0x114>(v);  // row_shr:4
  v = dadd<0x118>(v);  // row_shr:8
  v = dadd<0x142>(v);  // row_bcast:15
  v = dadd<0x143>(v);  // row_bcast:31
  return v;            // lane 63 = full sum
}

// fast tanh: 1 - 2/(e^{2x}+1) via native exp2/rcp. ~1e-7 abs, branch-free.
// PROVEN absmax 0.0 in R23-R30.
__device__ inline float ftanh(float x) {
  float e = __builtin_amdgcn_exp2f(x * 2.8853900817779268f);  // e^{2x}
  float r = __builtin_amdgcn_rcpf(e + 1.0f);
  return fmaf(-2.0f, r, 1.0f);
}

// 32-block barrier, fence-free (all cross-block data via agent-scope atomics).
__device__ inline void gbar(int* cnt, int phase, int tid) {
  __syncthreads();
  if (tid == 0) {
    __hip_atomic_fetch_add(&cnt[phase], 1, __ATOMIC_RELEASE,
                           __HIP_MEMORY_SCOPE_AGENT);
    while (__hip_atomic_load(&cnt[phase], __ATOMIC_RELAXED,
                             __HIP_MEMORY_SCOPE_AGENT) < B)
      __builtin_amdgcn_s_sleep(2);
  }
  __syncthreads();
}

__global__ void __launch_bounds__(NT) fused23(Params p) {
  const int b = blockIdx.x, tid = threadIdx.x;
  const int lane = tid & 63, wid = tid >> 6;   // 8 waves
  const int t0 = tid, t1 = tid + NT;

  __shared__ __align__(16) float slab[T * 11];   // scratch, then Iin [h][RS]
  __shared__ __align__(16) float gtab[T];        // 4KB
  __shared__ double dred2[60 * 17 + 4];          // combine partials (pad 17)
  __shared__ double dtot[60];
  __shared__ float stM[30], stI[30], Ms[100], Nl[100];

  // slab scratch layout (all dead before S5 overwrites the whole slab):
  //  swred [0,480) | kxt [0,10240) (lifetime-disjoint) | mpw [10240,11040)
  float* swred = slab;
  float* kxt   = slab;
  float* mpw   = slab + 10240;

  // g[t] = (9(1-0.9^{T-t}) - 4(1-0.8^{T-t})) / T  (f32 closed form)
  {
    const float L2A = -0.15200309344504995f;   // log2(0.9)
    const float L2D = -0.32192809488736235f;   // log2(0.8)
    float m0 = (float)(T - t0), m1 = (float)(T - t1);
    gtab[t0] = (9.0f * (1.0f - exp2f(m0 * L2A)) -
                4.0f * (1.0f - exp2f(m0 * L2D))) * (1.0f / (float)T);
    gtab[t1] = (9.0f * (1.0f - exp2f(m1 * L2A)) -
                4.0f * (1.0f - exp2f(m1 * L2D))) * (1.0f / (float)T);
  }

  // parallel stats combine: P layout [ch][32]; ch x 16 workers, 2 loads each.
  auto combine = [&](double* P, int Q2) {
    for (int id = tid; id < Q2 * 16; id += NT) {
      int ch = id >> 4, i = id & 15;
      double s = __hip_atomic_load(&P[ch * 32 + i], __ATOMIC_RELAXED,
                                   __HIP_MEMORY_SCOPE_AGENT) +
                 __hip_atomic_load(&P[ch * 32 + 16 + i], __ATOMIC_RELAXED,
                                   __HIP_MEMORY_SCOPE_AGENT);
      dred2[ch * 17 + i] = s;
    }
    __syncthreads();
    if (tid < Q2) {
      double s = 0.0;
#pragma unroll
      for (int i = 0; i < 16; ++i) s += dred2[tid * 17 + i];
      dtot[tid] = s;
    }
    __syncthreads();
  };

  // ---------------- S1: embed (weights via uniform/scalar loads; pk-fma)
  v2f p1[H];
#pragma unroll
  for (int h = 0; h < H; ++h) p1[h] = v2(p.b_ef[h]);
  {
    const float* bp = p.beeg + (size_t)b * C * T;
#pragma unroll 8
    for (int c = 0; c < C; ++c) {
      v2f vab;
      vab.x = bp[(size_t)c * T + t0];
      vab.y = bp[(size_t)c * T + t1];
#pragma unroll
      for (int h = 0; h < H; ++h)
        p1[h] = vfma(vab, v2(p.W_ef[h * C + c]), p1[h]);
    }
  }
#pragma unroll
  for (int h = 0; h < H; ++h) {
    float r1 = wred63(p1[h].x + p1[h].y);
    float r2 = wred63(p1[h].x * p1[h].x + p1[h].y * p1[h].y);
    if (lane == 63) { swred[wid * 60 + h] = r1; swred[wid * 60 + 10 + h] = r2; }
  }
  __syncthreads();
  if (tid < 20) {
    float s = 0.f;
#pragma unroll
    for (int w = 0; w < 8; ++w) s += swred[w * 60 + tid];
    __hip_atomic_store(&p.P1[tid * 32 + b], (double)s, __ATOMIC_RELAXED,
                       __HIP_MEMORY_SCOPE_AGENT);
  }
  gbar(p.cnt, 0, tid);
  combine(p.P1, 20);
  if (tid < 10) {
    double mean = dtot[tid] * (1.0 / 32768.0);
    double var  = dtot[10 + tid] * (1.0 / 32768.0) - mean * mean;
    stM[tid] = (float)mean;
    stI[tid] = (float)(1.0 / sqrt(var + 1e-5));
  }
  __syncthreads();

  // ---------------- S2: x = tanh(bn(pre1)); qkv stats (pk-fma accums)
  v2f xv[H];
#pragma unroll
  for (int j = 0; j < H; ++j) {
    xv[j].x = ftanh(p.g_i[j] * (p1[j].x - stM[j]) * stI[j] + p.be_i[j]);
    xv[j].y = ftanh(p.g_i[j] * (p1[j].y - stM[j]) * stI[j] + p.be_i[j]);
  }
  // p1 dead; only xv (10 v2f) persists from here on.
#pragma unroll
  for (int h = 0; h < H; ++h) {
    v2f q = v2(0.f), k = v2(0.f), v = v2(0.f);
#pragma unroll
    for (int j = 0; j < H; ++j) {
      q = vfma(xv[j], v2(p.Wq[h * H + j]), q);
      k = vfma(xv[j], v2(p.Wk[h * H + j]), k);
      v = vfma(xv[j], v2(p.Wv[h * H + j]), v);
    }
    float r1 = wred63(q.x + q.y), r2 = wred63(q.x * q.x + q.y * q.y);
    float r3 = wred63(k.x + k.y), r4 = wred63(k.x * k.x + k.y * k.y);
    float r5 = wred63(v.x + v.y), r6 = wred63(v.x * v.x + v.y * v.y);
    if (lane == 63) {
      swred[wid * 60 + h]      = r1; swred[wid * 60 + 30 + h] = r2;
      swred[wid * 60 + 10 + h] = r3; swred[wid * 60 + 40 + h] = r4;
      swred[wid * 60 + 20 + h] = r5; swred[wid * 60 + 50 + h] = r6;
    }
  }
  __syncthreads();
  if (tid < 60) {
    float s = 0.f;
#pragma unroll
    for (int w = 0; w < 8; ++w) s += swred[w * 60 + tid];
    __hip_atomic_store(&p.P2[tid * 32 + b], (double)s, __ATOMIC_RELAXED,
                       __HIP_MEMORY_SCOPE_AGENT);
  }
  gbar(p.cnt, 1, tid);
  combine(p.P2, 60);
  if (tid < 30) {
    double mean = dtot[tid] * (1.0 / 32768.0);
    double var  = dtot[30 + tid] * (1.0 / 32768.0) - mean * mean;
    stM[tid] = (float)mean;
    stI[tid] = (float)(1.0 / sqrt(var + 1e-5));
  }
  __syncthreads();   // swred reads done; kxt may now overwrite [0,480)

  // ---------------- S3: M = KV^T, merged single pass (R28 structure,
  // pk-fma mats). kxt transposed [20][512]: conflict-free.
  {
    v2f vx[H];   // (vxa, vxb)
#pragma unroll
    for (int h = 0; h < H; ++h) {
      v2f k = v2(0.f), v = v2(0.f);
#pragma unroll
      for (int j = 0; j < H; ++j) {
        k = vfma(xv[j], v2(p.Wk[h * H + j]), k);
        v = vfma(xv[j], v2(p.Wv[h * H + j]), v);
      }
      kxt[h * NT + tid] =
          fmaxf(p.g_k[h] * (k.x - stM[10 + h]) * stI[10 + h] + p.be_k[h], 0.f);
      kxt[(H + h) * NT + tid] =
          fmaxf(p.g_k[h] * (k.y - stM[10 + h]) * stI[10 + h] + p.be_k[h], 0.f);
      vx[h].x = ftanh(p.g_v[h] * (v.x - stM[20 + h]) * stI[20 + h] + p.be_v[h]);
      vx[h].y = ftanh(p.g_v[h] * (v.y - stM[20 + h]) * stI[20 + h] + p.be_v[h]);
    }
    __syncthreads();   // kxt writes visible (also orders vs swred aliasing)
#pragma unroll 1
    for (int i = 0; i < H; ++i) {
      float kia = kxt[i * NT + tid];
      float kib = kxt[(H + i) * NT + tid];
#pragma unroll
      for (int j = 0; j < H; ++j) {
        float r = wred63(fmaf(kia, vx[j].x, kib * vx[j].y));
        if (lane == 63) mpw[wid * 100 + i * 10 + j] = r;
      }
    }
  }
  __syncthreads();
  if (tid < 100) {
    float s = 0.f;
#pragma unroll
    for (int w = 0; w < 8; ++w) s += mpw[w * 100 + tid];
    Ms[tid] = s;
  }
  __syncthreads();

  // ---------------- S4: N = (M Wc^T)/H; recompute q; prec = q.N (pk)
  if (tid < 100) {
    int i = tid / 10, h = tid % 10;
    float a = 0.f;
#pragma unroll
    for (int j = 0; j < H; ++j) a = fmaf(Ms[i * 10 + j], p.Wc[h * H + j], a);
    Nl[tid] = a * 0.1f;
  }
  __syncthreads();
  v2f pc[H];
  {
    v2f qv[H];
#pragma unroll
    for (int h = 0; h < H; ++h) {
      v2f qa = v2(0.f);
#pragma unroll
      for (int j = 0; j < H; ++j) qa = vfma(xv[j], v2(p.Wq[h * H + j]), qa);
      qv[h].x = fmaxf(p.g_q[h] * (qa.x - stM[h]) * stI[h] + p.be_q[h], 0.f);
      qv[h].y = fmaxf(p.g_q[h] * (qa.y - stM[h]) * stI[h] + p.be_q[h], 0.f);
    }
#pragma unroll
    for (int h = 0; h < H; ++h) {
      v2f a = v2(0.f);
#pragma unroll
      for (int i = 0; i < H; ++i) a = vfma(qv[i], v2(Nl[i * 10 + h]), a);
      pc[h] = a;
    }
  }
  // xv dead now; pc (10 v2f) live.
#pragma unroll
  for (int h = 0; h < H; ++h) {
    float r1 = wred63(pc[h].x + pc[h].y);
    float r2 = wred63(pc[h].x * pc[h].x + pc[h].y * pc[h].y);
    if (lane == 63) { swred[wid * 60 + h] = r1; swred[wid * 60 + 10 + h] = r2; }
  }
  __syncthreads();
  if (tid < 20) {
    float s = 0.f;
#pragma unroll
    for (int w = 0; w < 8; ++w) s += swred[w * 60 + tid];
    __hip_atomic_store(&p.P3[tid * 32 + b], (double)s, __ATOMIC_RELAXED,
                       __HIP_MEMORY_SCOPE_AGENT);
  }
  gbar(p.cnt, 2, tid);
  combine(p.P3, 20);
  if (tid < 10) {
    double mean = dtot[tid] * (1.0 / 32768.0);
    double var  = dtot[10 + tid] * (1.0 / 32768.0) - mean * mean;
    stM[tid] = (float)mean;
    stI[tid] = (float)(1.0 / sqrt(var + 1e-5));
  }
  __syncthreads();   // all slab-scratch reads done before S5 overwrites

  // ---------------- S5: bn+relu, Iin into LDS rows [h][RS] (pk-fma)
  {
    v2f ca[H];
#pragma unroll
    for (int j = 0; j < H; ++j) {
      ca[j].x = fmaxf(p.g_c[j] * (pc[j].x - stM[j]) * stI[j] + p.be_c[j], 0.f);
      ca[j].y = fmaxf(p.g_c[j] * (pc[j].y - stM[j]) * stI[j] + p.be_c[j], 0.f);
    }
#pragma unroll
    for (int h = 0; h < H; ++h) {
      v2f a = v2(0.f);
#pragma unroll
      for (int j = 0; j < H; ++j) a = vfma(ca[j], v2(p.W_in[h * H + j]), a);
      slab[h * RS + t0] = a.x;
      slab[h * RS + t1] = a.y;
    }
  }
  __syncthreads();

  // ---------------- S6: LSNN scan, wave 0 only; dual fma chains + fused
  // decay; ping-pong 16-step unroll (no buffer copies; bit-exact).
  if (tid < 64) {
    // gtot closed form: .9^1024/.8^1024 underflow -> (5*1024 - 81 + 16)/1024
    const float gtot = 4.9365234375f;

    const int slot = lane < H ? lane : 0;   // inactive lanes broadcast row 0
    const float* row = slab + slot * RS;
    float wrf[H];                           // W_rec row (this lane's neuron)
#pragma unroll
    for (int j = 0; j < H; ++j)
      wrf[j] = (lane < H) ? p.W_rec[lane * H + j] : 0.f;

    float accp = 0.f, vm = 0.f, S = 0.f;    // accp = i_jump of prev step
    float zf = 0.f;   // prev-step spike, per-lane float (lane j holds z_j)

    auto step = [&](float iin, float gt) {
      float zj[H];
#pragma unroll
      for (int j = 0; j < H; ++j)
        zj[j] = __int_as_float(
            __builtin_amdgcn_readlane(__float_as_int(zf), j));
      float acc0 = fmaf(0.8f, accp, iin);   // fused decay
      float acc1 = 0.f;
#pragma unroll
      for (int j = 0; j < H; j += 2) {      // dual chains
        acc0 = fmaf(zj[j],     wrf[j],     acc0);
        acc1 = fmaf(zj[j + 1], wrf[j + 1], acc1);
      }
      float acc = acc0 + acc1;
      float v_dec = fmaf(0.1f, acc - vm, vm);  // vm + 0.1*(i_jump - vm)
      bool z = v_dec > 0.5f;
      vm = z ? 0.f : v_dec;
      zf = z ? 1.0f : 0.0f;
      S = fmaf(zf, gt, S);                     // exact: +gt or +0.0
      accp = acc;
    };

    float4 iA0 = *(const float4*)&row[0];
    float4 iA1 = *(const float4*)&row[4];
    float4 gA0 = *(const float4*)&gtab[0], gA1 = *(const float4*)&gtab[4];

    for (int t16 = 0; t16 < T - 16; t16 += 16) {
      float4 iB0 = *(const float4*)&row[t16 + 8];
      float4 iB1 = *(const float4*)&row[t16 + 12];
      float4 gB0 = *(const float4*)&gtab[t16 + 8];
      float4 gB1 = *(const float4*)&gtab[t16 + 12];
      step(iA0.x, gA0.x); step(iA0.y, gA0.y);
      step(iA0.z, gA0.z); step(iA0.w, gA0.w);
      step(iA1.x, gA1.x); step(iA1.y, gA1.y);
      step(iA1.z, gA1.z); step(iA1.w, gA1.w);
      iA0 = *(const float4*)&row[t16 + 16];
      iA1 = *(const float4*)&row[t16 + 20];
      gA0 = *(const float4*)&gtab[t16 + 16];
      gA1 = *(const float4*)&gtab[t16 + 20];
      step(iB0.x, gB0.x); step(iB0.y, gB0.y);
      step(iB0.z, gB0.z); step(iB0.w, gB0.w);
      step(iB1.x, gB1.x); step(iB1.y, gB1.y);
      step(iB1.z, gB1.z); step(iB1.w, gB1.w);
    }
    // t16 == T-16 here; A buffers hold row[T-16..T-9]
    {
      float4 iB0 = *(const float4*)&row[T - 8];
      float4 iB1 = *(const float4*)&row[T - 4];
      float4 gB0 = *(const float4*)&gtab[T - 8];
      float4 gB1 = *(const float4*)&gtab[T - 4];
      step(iA0.x, gA0.x); step(iA0.y, gA0.y);
      step(iA0.z, gA0.z); step(iA0.w, gA0.w);
      step(iA1.x, gA1.x); step(iA1.y, gA1.y);
      step(iA1.z, gA1.z); step(iA1.w, gA1.w);
      step(iB0.x, gB0.x); step(iB0.y, gB0.y);
      step(iB0.z, gB0.z); step(iB0.w, gB0.w);
      step(iB1.x, gB1.x); step(iB1.y, gB1.y);
      step(iB1.z, gB1.z); step(iB1.w, gB1.w);
    }

    int li = lane < H ? lane : 0;
    float c0 = (lane < H) ? S * p.W_cls[li]     : 0.f;
    float c1 = (lane < H) ? S * p.W_cls[H + li] : 0.f;
    float r0 = wred63(c0), r1 = wred63(c1);
    if (lane == 63) {
      p.out[b * 2 + 0] = r0 + gtot * p.b_cls[0];
      p.out[b * 2 + 1] = r1 + gtot * p.b_cls[1];
    }
  }
}

extern "C" void kernel_launch(void* const* d_in, const int* in_sizes, int n_in,
                              void* d_out, int out_size, void* d_ws, size_t ws_size,
                              hipStream_t stream) {
  Params p;
  p.beeg  = (const float*)d_in[2];
  p.W_ef  = (const float*)d_in[4];
  p.b_ef  = (const float*)d_in[5];
  p.g_i   = (const float*)d_in[6];
  p.be_i  = (const float*)d_in[7];
  p.Wq    = (const float*)d_in[8];
  p.g_q   = (const float*)d_in[9];
  p.be_q  = (const float*)d_in[10];
  p.Wk    = (const float*)d_in[11];
  p.g_k   = (const float*)d_in[12];
  p.be_k  = (const float*)d_in[13];
  p.Wv    = (const float*)d_in[14];
  p.g_v   = (const float*)d_in[15];
  p.be_v  = (const float*)d_in[16];
  p.Wc    = (const float*)d_in[17];
  p.g_c   = (const float*)d_in[18];
  p.be_c  = (const float*)d_in[19];
  p.W_in  = (const float*)d_in[20];
  p.W_rec = (const float*)d_in[21];
  p.W_cls = (const float*)d_in[22];
  p.b_cls = (const float*)d_in[23];

  char* ws = (char*)d_ws;
  p.cnt = (int*)ws;                            // 3 counters, memset below
  p.P1  = (double*)(ws + 256);                 // [20][32] doubles
  p.P2  = (double*)(ws + 256 + 5120);          // [60][32] doubles
  p.P3  = (double*)(ws + 256 + 5120 + 15360);  // [20][32] doubles
  p.out = (float*)d_out;

  (void)hipMemsetAsync(d_ws, 0, 256, stream);  // zero barrier counters
  fused23<<<dim3(B), dim3(NT), 0, stream>>>(p);
}

// Round 17
// 200.279 us; speedup vs baseline: 1.0372x; 1.0118x over previous
//
#include <hip/hip_runtime.h>
#include <math.h>

// Model: B=32, C=64, T=1024, H=10, OUT=2.
// R31 post-mortem: ping-pong NEUTRAL (98.1us) -- compiler had already
// renamed the buffer copies. Split: parallel ~35.5us, scan ~62.5us
// (153 cyc/step @ 26 instrs). Calibration: -1 instr/step ~= -2us.
// R32 = R31 + ONE change: rec dot back to the SINGLE serial fma chain
// (drops the dual-chain merge add) -> 25 instrs/step. This is exactly
// R24's proven scan numerics (fused decay + serial chain, absmax 0.0).
// Serial latency 80cyc < issue ~105cyc (R26: latency slack exists).
// Predict: dur 98.1 -> ~96-97, absmax 0.0, counters unchanged.
// PRE-COMMIT: if >=97.5 (neutral), declare structural floor next round:
// serial 1024-step scan @ lone-wave cadence (~60us irreducible) +
// parallel ~35us that resisted CU-scaling/occupancy/code-size attacks.

constexpr int B = 32, C = 64, T = 1024, H = 10;
constexpr int NT = 512;   // threads per block (8 waves)
constexpr int RS = 1028;  // scan-row stride (floats): 16B-aligned

using v2f = float __attribute__((ext_vector_type(2)));
__device__ inline v2f v2(float s) { v2f r; r.x = s; r.y = s; return r; }
__device__ inline v2f vfma(v2f a, v2f b, v2f c) {
  return __builtin_elementwise_fma(a, b, c);   // v_pk_fma_f32
}

struct Params {
  const float *beeg, *W_ef, *b_ef, *g_i, *be_i, *Wq, *g_q, *be_q, *Wk, *g_k,
      *be_k, *Wv, *g_v, *be_v, *Wc, *g_c, *be_c, *W_in, *W_rec, *W_cls, *b_cls;
  int* cnt;              // barrier counters (memset 0 each launch)
  double *P1, *P2, *P3;  // cross-block stat partials, layout [ch][32]
  float* out;
};

// DPP wave64 sum: result valid in lane 63 (VALU pipe, no DS traffic).
template <int CTRL>
__device__ inline float dadd(float v) {
  int x = __builtin_amdgcn_update_dpp(0, __float_as_int(v), CTRL, 0xf, 0xf,
                                      true);
  return v + __int_as_float(x);
}
__device__ inline float wred63(float v) {
  v = dadd<0x111>(v);  // row_shr:1
  v = dadd<0x112>(v);  // row_shr:2
  v = dadd<0x114>(v);  // row_shr:4
  v = dadd<0x118>(v);  // row_shr:8
  v = dadd<0x142>(v);  // row_bcast:15
  v = dadd<0x143>(v);  // row_bcast:31
  return v;            // lane 63 = full sum
}

// fast tanh: 1 - 2/(e^{2x}+1) via native exp2/rcp. ~1e-7 abs, branch-free.
// PROVEN absmax 0.0 in R23-R31.
__device__ inline float ftanh(float x) {
  float e = __builtin_amdgcn_exp2f(x * 2.8853900817779268f);  // e^{2x}
  float r = __builtin_amdgcn_rcpf(e + 1.0f);
  return fmaf(-2.0f, r, 1.0f);
}

// 32-block barrier, fence-free (all cross-block data via agent-scope atomics).
__device__ inline void gbar(int* cnt, int phase, int tid) {
  __syncthreads();
  if (tid == 0) {
    __hip_atomic_fetch_add(&cnt[phase], 1, __ATOMIC_RELEASE,
                           __HIP_MEMORY_SCOPE_AGENT);
    while (__hip_atomic_load(&cnt[phase], __ATOMIC_RELAXED,
                             __HIP_MEMORY_SCOPE_AGENT) < B)
      __builtin_amdgcn_s_sleep(2);
  }
  __syncthreads();
}

__global__ void __launch_bounds__(NT) fused24(Params p) {
  const int b = blockIdx.x, tid = threadIdx.x;
  const int lane = tid & 63, wid = tid >> 6;   // 8 waves
  const int t0 = tid, t1 = tid + NT;

  __shared__ __align__(16) float slab[T * 11];   // scratch, then Iin [h][RS]
  __shared__ __align__(16) float gtab[T];        // 4KB
  __shared__ double dred2[60 * 17 + 4];          // combine partials (pad 17)
  __shared__ double dtot[60];
  __shared__ float stM[30], stI[30], Ms[100], Nl[100];

  // slab scratch layout (all dead before S5 overwrites the whole slab):
  //  swred [0,480) | kxt [0,10240) (lifetime-disjoint) | mpw [10240,11040)
  float* swred = slab;
  float* kxt   = slab;
  float* mpw   = slab + 10240;

  // g[t] = (9(1-0.9^{T-t}) - 4(1-0.8^{T-t})) / T  (f32 closed form)
  {
    const float L2A = -0.15200309344504995f;   // log2(0.9)
    const float L2D = -0.32192809488736235f;   // log2(0.8)
    float m0 = (float)(T - t0), m1 = (float)(T - t1);
    gtab[t0] = (9.0f * (1.0f - exp2f(m0 * L2A)) -
                4.0f * (1.0f - exp2f(m0 * L2D))) * (1.0f / (float)T);
    gtab[t1] = (9.0f * (1.0f - exp2f(m1 * L2A)) -
                4.0f * (1.0f - exp2f(m1 * L2D))) * (1.0f / (float)T);
  }

  // parallel stats combine: P layout [ch][32]; ch x 16 workers, 2 loads each.
  auto combine = [&](double* P, int Q2) {
    for (int id = tid; id < Q2 * 16; id += NT) {
      int ch = id >> 4, i = id & 15;
      double s = __hip_atomic_load(&P[ch * 32 + i], __ATOMIC_RELAXED,
                                   __HIP_MEMORY_SCOPE_AGENT) +
                 __hip_atomic_load(&P[ch * 32 + 16 + i], __ATOMIC_RELAXED,
                                   __HIP_MEMORY_SCOPE_AGENT);
      dred2[ch * 17 + i] = s;
    }
    __syncthreads();
    if (tid < Q2) {
      double s = 0.0;
#pragma unroll
      for (int i = 0; i < 16; ++i) s += dred2[tid * 17 + i];
      dtot[tid] = s;
    }
    __syncthreads();
  };

  // ---------------- S1: embed (weights via uniform/scalar loads; pk-fma)
  v2f p1[H];
#pragma unroll
  for (int h = 0; h < H; ++h) p1[h] = v2(p.b_ef[h]);
  {
    const float* bp = p.beeg + (size_t)b * C * T;
#pragma unroll 8
    for (int c = 0; c < C; ++c) {
      v2f vab;
      vab.x = bp[(size_t)c * T + t0];
      vab.y = bp[(size_t)c * T + t1];
#pragma unroll
      for (int h = 0; h < H; ++h)
        p1[h] = vfma(vab, v2(p.W_ef[h * C + c]), p1[h]);
    }
  }
#pragma unroll
  for (int h = 0; h < H; ++h) {
    float r1 = wred63(p1[h].x + p1[h].y);
    float r2 = wred63(p1[h].x * p1[h].x + p1[h].y * p1[h].y);
    if (lane == 63) { swred[wid * 60 + h] = r1; swred[wid * 60 + 10 + h] = r2; }
  }
  __syncthreads();
  if (tid < 20) {
    float s = 0.f;
#pragma unroll
    for (int w = 0; w < 8; ++w) s += swred[w * 60 + tid];
    __hip_atomic_store(&p.P1[tid * 32 + b], (double)s, __ATOMIC_RELAXED,
                       __HIP_MEMORY_SCOPE_AGENT);
  }
  gbar(p.cnt, 0, tid);
  combine(p.P1, 20);
  if (tid < 10) {
    double mean = dtot[tid] * (1.0 / 32768.0);
    double var  = dtot[10 + tid] * (1.0 / 32768.0) - mean * mean;
    stM[tid] = (float)mean;
    stI[tid] = (float)(1.0 / sqrt(var + 1e-5));
  }
  __syncthreads();

  // ---------------- S2: x = tanh(bn(pre1)); qkv stats (pk-fma accums)
  v2f xv[H];
#pragma unroll
  for (int j = 0; j < H; ++j) {
    xv[j].x = ftanh(p.g_i[j] * (p1[j].x - stM[j]) * stI[j] + p.be_i[j]);
    xv[j].y = ftanh(p.g_i[j] * (p1[j].y - stM[j]) * stI[j] + p.be_i[j]);
  }
  // p1 dead; only xv (10 v2f) persists from here on.
#pragma unroll
  for (int h = 0; h < H; ++h) {
    v2f q = v2(0.f), k = v2(0.f), v = v2(0.f);
#pragma unroll
    for (int j = 0; j < H; ++j) {
      q = vfma(xv[j], v2(p.Wq[h * H + j]), q);
      k = vfma(xv[j], v2(p.Wk[h * H + j]), k);
      v = vfma(xv[j], v2(p.Wv[h * H + j]), v);
    }
    float r1 = wred63(q.x + q.y), r2 = wred63(q.x * q.x + q.y * q.y);
    float r3 = wred63(k.x + k.y), r4 = wred63(k.x * k.x + k.y * k.y);
    float r5 = wred63(v.x + v.y), r6 = wred63(v.x * v.x + v.y * v.y);
    if (lane == 63) {
      swred[wid * 60 + h]      = r1; swred[wid * 60 + 30 + h] = r2;
      swred[wid * 60 + 10 + h] = r3; swred[wid * 60 + 40 + h] = r4;
      swred[wid * 60 + 20 + h] = r5; swred[wid * 60 + 50 + h] = r6;
    }
  }
  __syncthreads();
  if (tid < 60) {
    float s = 0.f;
#pragma unroll
    for (int w = 0; w < 8; ++w) s += swred[w * 60 + tid];
    __hip_atomic_store(&p.P2[tid * 32 + b], (double)s, __ATOMIC_RELAXED,
                       __HIP_MEMORY_SCOPE_AGENT);
  }
  gbar(p.cnt, 1, tid);
  combine(p.P2, 60);
  if (tid < 30) {
    double mean = dtot[tid] * (1.0 / 32768.0);
    double var  = dtot[30 + tid] * (1.0 / 32768.0) - mean * mean;
    stM[tid] = (float)mean;
    stI[tid] = (float)(1.0 / sqrt(var + 1e-5));
  }
  __syncthreads();   // swred reads done; kxt may now overwrite [0,480)

  // ---------------- S3: M = KV^T, merged single pass (R28 structure,
  // pk-fma mats). kxt transposed [20][512]: conflict-free.
  {
    v2f vx[H];   // (vxa, vxb)
#pragma unroll
    for (int h = 0; h < H; ++h) {
      v2f k = v2(0.f), v = v2(0.f);
#pragma unroll
      for (int j = 0; j < H; ++j) {
        k = vfma(xv[j], v2(p.Wk[h * H + j]), k);
        v = vfma(xv[j], v2(p.Wv[h * H + j]), v);
      }
      kxt[h * NT + tid] =
          fmaxf(p.g_k[h] * (k.x - stM[10 + h]) * stI[10 + h] + p.be_k[h], 0.f);
      kxt[(H + h) * NT + tid] =
          fmaxf(p.g_k[h] * (k.y - stM[10 + h]) * stI[10 + h] + p.be_k[h], 0.f);
      vx[h].x = ftanh(p.g_v[h] * (v.x - stM[20 + h]) * stI[20 + h] + p.be_v[h]);
      vx[h].y = ftanh(p.g_v[h] * (v.y - stM[20 + h]) * stI[20 + h] + p.be_v[h]);
    }
    __syncthreads();   // kxt writes visible (also orders vs swred aliasing)
#pragma unroll 1
    for (int i = 0; i < H; ++i) {
      float kia = kxt[i * NT + tid];
      float kib = kxt[(H + i) * NT + tid];
#pragma unroll
      for (int j = 0; j < H; ++j) {
        float r = wred63(fmaf(kia, vx[j].x, kib * vx[j].y));
        if (lane == 63) mpw[wid * 100 + i * 10 + j] = r;
      }
    }
  }
  __syncthreads();
  if (tid < 100) {
    float s = 0.f;
#pragma unroll
    for (int w = 0; w < 8; ++w) s += mpw[w * 100 + tid];
    Ms[tid] = s;
  }
  __syncthreads();

  // ---------------- S4: N = (M Wc^T)/H; recompute q; prec = q.N (pk)
  if (tid < 100) {
    int i = tid / 10, h = tid % 10;
    float a = 0.f;
#pragma unroll
    for (int j = 0; j < H; ++j) a = fmaf(Ms[i * 10 + j], p.Wc[h * H + j], a);
    Nl[tid] = a * 0.1f;
  }
  __syncthreads();
  v2f pc[H];
  {
    v2f qv[H];
#pragma unroll
    for (int h = 0; h < H; ++h) {
      v2f qa = v2(0.f);
#pragma unroll
      for (int j = 0; j < H; ++j) qa = vfma(xv[j], v2(p.Wq[h * H + j]), qa);
      qv[h].x = fmaxf(p.g_q[h] * (qa.x - stM[h]) * stI[h] + p.be_q[h], 0.f);
      qv[h].y = fmaxf(p.g_q[h] * (qa.y - stM[h]) * stI[h] + p.be_q[h], 0.f);
    }
#pragma unroll
    for (int h = 0; h < H; ++h) {
      v2f a = v2(0.f);
#pragma unroll
      for (int i = 0; i < H; ++i) a = vfma(qv[i], v2(Nl[i * 10 + h]), a);
      pc[h] = a;
    }
  }
  // xv dead now; pc (10 v2f) live.
#pragma unroll
  for (int h = 0; h < H; ++h) {
    float r1 = wred63(pc[h].x + pc[h].y);
    float r2 = wred63(pc[h].x * pc[h].x + pc[h].y * pc[h].y);
    if (lane == 63) { swred[wid * 60 + h] = r1; swred[wid * 60 + 10 + h] = r2; }
  }
  __syncthreads();
  if (tid < 20) {
    float s = 0.f;
#pragma unroll
    for (int w = 0; w < 8; ++w) s += swred[w * 60 + tid];
    __hip_atomic_store(&p.P3[tid * 32 + b], (double)s, __ATOMIC_RELAXED,
                       __HIP_MEMORY_SCOPE_AGENT);
  }
  gbar(p.cnt, 2, tid);
  combine(p.P3, 20);
  if (tid < 10) {
    double mean = dtot[tid] * (1.0 / 32768.0);
    double var  = dtot[10 + tid] * (1.0 / 32768.0) - mean * mean;
    stM[tid] = (float)mean;
    stI[tid] = (float)(1.0 / sqrt(var + 1e-5));
  }
  __syncthreads();   // all slab-scratch reads done before S5 overwrites

  // ---------------- S5: bn+relu, Iin into LDS rows [h][RS] (pk-fma)
  {
    v2f ca[H];
#pragma unroll
    for (int j = 0; j < H; ++j) {
      ca[j].x = fmaxf(p.g_c[j] * (pc[j].x - stM[j]) * stI[j] + p.be_c[j], 0.f);
      ca[j].y = fmaxf(p.g_c[j] * (pc[j].y - stM[j]) * stI[j] + p.be_c[j], 0.f);
    }
#pragma unroll
    for (int h = 0; h < H; ++h) {
      v2f a = v2(0.f);
#pragma unroll
      for (int j = 0; j < H; ++j) a = vfma(ca[j], v2(p.W_in[h * H + j]), a);
      slab[h * RS + t0] = a.x;
      slab[h * RS + t1] = a.y;
    }
  }
  __syncthreads();

  // ---------------- S6: LSNN scan, wave 0 only; R24-proven serial fma
  // chain + fused decay (25 instrs/step).
  if (tid < 64) {
    // gtot closed form: .9^1024/.8^1024 underflow -> (5*1024 - 81 + 16)/1024
    const float gtot = 4.9365234375f;

    const int slot = lane < H ? lane : 0;   // inactive lanes broadcast row 0
    const float* row = slab + slot * RS;
    float wrf[H];                           // W_rec row (this lane's neuron)
#pragma unroll
    for (int j = 0; j < H; ++j)
      wrf[j] = (lane < H) ? p.W_rec[lane * H + j] : 0.f;

    float accp = 0.f, vm = 0.f, S = 0.f;    // accp = i_jump of prev step
    float zf = 0.f;   // prev-step spike, per-lane float (lane j holds z_j)

    auto step = [&](float iin, float gt) {
      float acc = fmaf(0.8f, accp, iin);    // fused decay (R24-proven)
#pragma unroll
      for (int j = 0; j < H; ++j) {         // serial chain (R24-proven)
        float zj = __int_as_float(
            __builtin_amdgcn_readlane(__float_as_int(zf), j));
        acc = fmaf(zj, wrf[j], acc);
      }
      float v_dec = fmaf(0.1f, acc - vm, vm);  // vm + 0.1*(i_jump - vm)
      bool z = v_dec > 0.5f;
      vm = z ? 0.f : v_dec;
      zf = z ? 1.0f : 0.0f;
      S = fmaf(zf, gt, S);                     // exact: +gt or +0.0
      accp = acc;
    };

    float4 iA = *(const float4*)&row[0];
    float4 iB = *(const float4*)&row[4];
    float4 gA = *(const float4*)&gtab[0], gB = *(const float4*)&gtab[4];

    for (int t8 = 0; t8 < T - 8; t8 += 8) {
      float4 iN1 = *(const float4*)&row[t8 + 8];
      float4 iN2 = *(const float4*)&row[t8 + 12];
      float4 gN1 = *(const float4*)&gtab[t8 + 8];
      float4 gN2 = *(const float4*)&gtab[t8 + 12];
      step(iA.x, gA.x); step(iA.y, gA.y); step(iA.z, gA.z); step(iA.w, gA.w);
      step(iB.x, gB.x); step(iB.y, gB.y); step(iB.z, gB.z); step(iB.w, gB.w);
      iA = iN1; iB = iN2; gA = gN1; gB = gN2;
    }
    step(iA.x, gA.x); step(iA.y, gA.y); step(iA.z, gA.z); step(iA.w, gA.w);
    step(iB.x, gB.x); step(iB.y, gB.y); step(iB.z, gB.z); step(iB.w, gB.w);

    int li = lane < H ? lane : 0;
    float c0 = (lane < H) ? S * p.W_cls[li]     : 0.f;
    float c1 = (lane < H) ? S * p.W_cls[H + li] : 0.f;
    float r0 = wred63(c0), r1 = wred63(c1);
    if (lane == 63) {
      p.out[b * 2 + 0] = r0 + gtot * p.b_cls[0];
      p.out[b * 2 + 1] = r1 + gtot * p.b_cls[1];
    }
  }
}

extern "C" void kernel_launch(void* const* d_in, const int* in_sizes, int n_in,
                              void* d_out, int out_size, void* d_ws, size_t ws_size,
                              hipStream_t stream) {
  Params p;
  p.beeg  = (const float*)d_in[2];
  p.W_ef  = (const float*)d_in[4];
  p.b_ef  = (const float*)d_in[5];
  p.g_i   = (const float*)d_in[6];
  p.be_i  = (const float*)d_in[7];
  p.Wq    = (const float*)d_in[8];
  p.g_q   = (const float*)d_in[9];
  p.be_q  = (const float*)d_in[10];
  p.Wk    = (const float*)d_in[11];
  p.g_k   = (const float*)d_in[12];
  p.be_k  = (const float*)d_in[13];
  p.Wv    = (const float*)d_in[14];
  p.g_v   = (const float*)d_in[15];
  p.be_v  = (const float*)d_in[16];
  p.Wc    = (const float*)d_in[17];
  p.g_c   = (const float*)d_in[18];
  p.be_c  = (const float*)d_in[19];
  p.W_in  = (const float*)d_in[20];
  p.W_rec = (const float*)d_in[21];
  p.W_cls = (const float*)d_in[22];
  p.b_cls = (const float*)d_in[23];

  char* ws = (char*)d_ws;
  p.cnt = (int*)ws;                            // 3 counters, memset below
  p.P1  = (double*)(ws + 256);                 // [20][32] doubles
  p.P2  = (double*)(ws + 256 + 5120);          // [60][32] doubles
  p.P3  = (double*)(ws + 256 + 5120 + 15360);  // [20][32] doubles
  p.out = (float*)d_out;

  (void)hipMemsetAsync(d_ws, 0, 256, stream);  // zero barrier counters
  fused24<<<dim3(B), dim3(NT), 0, stream>>>(p);
}